// Round 2
// 2525.505 us; speedup vs baseline: 1.2147x; 1.2147x over previous
//
#include <hip/hip_runtime.h>
#include <cstddef>
#include <cstdint>

#define N_ROWS 2048
#define DM 1024
#define DMID 4096
#define DFEAT 16384

using u32 = unsigned int;
typedef float f32x4 __attribute__((ext_vector_type(4)));

__device__ __forceinline__ float relu_pos(float v) { return v > 0.f ? v : 0.f; }

// ---------------- init ----------------
__global__ void init_zero_kernel(int* a0, int* a1, int* a2, float* fs, int* is) {
  int t = blockIdx.x * 256 + threadIdx.x;
  if (t < DFEAT) a1[t] = 0;
  if (t < DMID) { a0[t] = 0; a2[t] = 0; }
  if (t < 4) { fs[t] = 0.f; is[t] = 0; }
}

// ---------------- dense fp32 GEMM + bias + relu ----------------
// C[M,N] = relu(A[M,K] @ W[K,N] + bias), 128x128x16 tile, 8x8 per thread.
__global__ __launch_bounds__(256) void gemm_relu_kernel(
    const float* __restrict__ A, const float* __restrict__ W,
    const float* __restrict__ bias, float* __restrict__ C,
    int M, int N, int K)
{
  __shared__ float As[16][132];
  __shared__ float Bs[16][132];
  const int tid = threadIdx.x;
  const int bn0 = blockIdx.x * 128;
  const int bm0 = blockIdx.y * 128;
  const int tx = tid & 15, ty = tid >> 4;
  float acc[8][8];
#pragma unroll
  for (int m = 0; m < 8; ++m)
#pragma unroll
    for (int n = 0; n < 8; ++n) acc[m][n] = 0.f;

  for (int k0 = 0; k0 < K; k0 += 16) {
#pragma unroll
    for (int it = 0; it < 2; ++it) {
      int li = tid + it * 256;
      int rr = li >> 2;
      int cc = (li & 3) << 2;
      float4 a = *(const float4*)&A[(size_t)(bm0 + rr) * K + k0 + cc];
      As[cc + 0][rr] = a.x; As[cc + 1][rr] = a.y;
      As[cc + 2][rr] = a.z; As[cc + 3][rr] = a.w;
    }
#pragma unroll
    for (int it = 0; it < 2; ++it) {
      int li = tid + it * 256;
      int rr = li >> 5;
      int cc = (li & 31) << 2;
      *(float4*)&Bs[rr][cc] = *(const float4*)&W[(size_t)(k0 + rr) * N + bn0 + cc];
    }
    __syncthreads();
#pragma unroll
    for (int kk = 0; kk < 16; ++kk) {
      float av[8], bv[8];
      *(float4*)&av[0] = *(const float4*)&As[kk][ty * 8];
      *(float4*)&av[4] = *(const float4*)&As[kk][ty * 8 + 4];
      *(float4*)&bv[0] = *(const float4*)&Bs[kk][tx * 8];
      *(float4*)&bv[4] = *(const float4*)&Bs[kk][tx * 8 + 4];
#pragma unroll
      for (int m = 0; m < 8; ++m)
#pragma unroll
        for (int n = 0; n < 8; ++n) acc[m][n] += av[m] * bv[n];
    }
    __syncthreads();
  }
#pragma unroll
  for (int m = 0; m < 8; ++m) {
    int rrow = bm0 + ty * 8 + m;
#pragma unroll
    for (int n4 = 0; n4 < 8; n4 += 4) {
      int ccol = bn0 + tx * 8 + n4;
      float4 o;
      o.x = relu_pos(acc[m][n4 + 0] + bias[ccol + 0]);
      o.y = relu_pos(acc[m][n4 + 1] + bias[ccol + 1]);
      o.z = relu_pos(acc[m][n4 + 2] + bias[ccol + 2]);
      o.w = relu_pos(acc[m][n4 + 3] + bias[ccol + 3]);
      *(float4*)&C[(size_t)rrow * N + ccol] = o;
    }
  }
}

// ---------------- exact per-row top-k (values >= 0) ----------------
template<int NW, bool DEAD>
__global__ __launch_bounds__(NW * 64) void topk_kernel(
    const float* __restrict__ src, int k, const int* __restrict__ dead,
    int* __restrict__ oidx, float* __restrict__ oval, int* __restrict__ ocnt)
{
  constexpr int B = NW * 64;
  constexpr int E = 16;
  const int tid = threadIdx.x;
  const int r = blockIdx.x;
  __shared__ int red[NW + 1];
  __shared__ int cnt_s, eq_s;
  u32 keys[E];
  const float* row = src + (size_t)r * (B * E);
#pragma unroll
  for (int j = 0; j < E; ++j) {
    int i = tid + j * B;
    float v = row[i];
    if (DEAD) keys[j] = dead[i] ? (__float_as_uint(v) + 1u) : 0u;
    else      keys[j] = __float_as_uint(v);
  }
  auto count_gt = [&](u32 x) -> int {
    int c = 0;
#pragma unroll
    for (int j = 0; j < E; ++j) c += (keys[j] > x) ? 1 : 0;
#pragma unroll
    for (int o = 32; o > 0; o >>= 1) c += __shfl_down(c, o, 64);
    if ((tid & 63) == 0) red[tid >> 6] = c;
    __syncthreads();
    if (tid == 0) {
      int t = 0;
#pragma unroll
      for (int w = 0; w < NW; ++w) t += red[w];
      red[NW] = t;
    }
    __syncthreads();
    return red[NW];
  };
  const u32 baseKey = DEAD ? 1u : 0u;
  int ck = count_gt(baseKey);
  u32 T;
  int take = 0;
  if (ck >= k) {
    u32 M = 0;
    for (int b = 30; b >= 0; --b) {
      u32 cand = M | (1u << b);
      int c = count_gt(cand);
      if (c >= k) M = cand;
    }
    T = M + 1u;
    int G = count_gt(T);
    take = (T > baseKey) ? (k - G) : 0;
  } else {
    T = baseKey;
  }
  if (tid == 0) { cnt_s = 0; eq_s = 0; }
  __syncthreads();
#pragma unroll
  for (int j = 0; j < E; ++j) {
    u32 kk = keys[j];
    if (kk > T) {
      int s = atomicAdd(&cnt_s, 1);
      oidx[(size_t)r * k + s] = tid + j * B;
      oval[(size_t)r * k + s] = __uint_as_float(DEAD ? (kk - 1u) : kk);
    }
  }
  __syncthreads();
  if (take > 0) {
#pragma unroll
    for (int j = 0; j < E; ++j) {
      if (keys[j] == T) {
        int e = atomicAdd(&eq_s, 1);
        if (e < take) {
          int s = atomicAdd(&cnt_s, 1);
          oidx[(size_t)r * k + s] = tid + j * B;
          oval[(size_t)r * k + s] = __uint_as_float(DEAD ? (T - 1u) : T);
        }
      }
    }
    __syncthreads();
  }
  if (tid == 0) ocnt[r] = cnt_s;
}

// ---------------- sparse-row x dense-W matmul, legacy 1024-col blocks ----------------
// kept for ncols=1024 sites (W_dec1). Unrolled x4 for MLP.
__global__ __launch_bounds__(256) void spmm_kernel(
    const int* __restrict__ sidx, const float* __restrict__ sval,
    const int* __restrict__ scnt, int kslots,
    const float* __restrict__ W, int ncols,
    const float* __restrict__ bias, float* __restrict__ out, int do_relu)
{
  __shared__ int si[512];
  __shared__ float sv[512];
  const int r = blockIdx.x;
  const int n = scnt[r];
  for (int i = threadIdx.x; i < n; i += 256) {
    si[i] = sidx[(size_t)r * kslots + i];
    sv[i] = sval[(size_t)r * kslots + i];
  }
  __syncthreads();
  const int c0 = blockIdx.y * 1024 + threadIdx.x * 4;
  float4 acc = *(const float4*)&bias[c0];
  const float* Wb = W + c0;
  int j = 0;
  for (; j + 4 <= n; j += 4) {
    int   i0 = si[j],     i1 = si[j + 1], i2 = si[j + 2], i3 = si[j + 3];
    float v0 = sv[j],     v1 = sv[j + 1], v2 = sv[j + 2], v3 = sv[j + 3];
    const float4 w0 = *(const float4*)&Wb[(size_t)i0 * ncols];
    const float4 w1 = *(const float4*)&Wb[(size_t)i1 * ncols];
    const float4 w2 = *(const float4*)&Wb[(size_t)i2 * ncols];
    const float4 w3 = *(const float4*)&Wb[(size_t)i3 * ncols];
    acc.x += v0 * w0.x; acc.y += v0 * w0.y; acc.z += v0 * w0.z; acc.w += v0 * w0.w;
    acc.x += v1 * w1.x; acc.y += v1 * w1.y; acc.z += v1 * w1.z; acc.w += v1 * w1.w;
    acc.x += v2 * w2.x; acc.y += v2 * w2.y; acc.z += v2 * w2.z; acc.w += v2 * w2.w;
    acc.x += v3 * w3.x; acc.y += v3 * w3.y; acc.z += v3 * w3.z; acc.w += v3 * w3.w;
  }
  for (; j < n; ++j) {
    float v = sv[j];
    const float4 w = *(const float4*)&Wb[(size_t)si[j] * ncols];
    acc.x += v * w.x; acc.y += v * w.y; acc.z += v * w.z; acc.w += v * w.w;
  }
  if (do_relu) {
    acc.x = relu_pos(acc.x); acc.y = relu_pos(acc.y);
    acc.z = relu_pos(acc.z); acc.w = relu_pos(acc.w);
  }
  *(float4*)&out[(size_t)r * ncols + c0] = acc;
}

// ---------------- L2-affine sparse-row x dense-W matmul ----------------
// 256-col slices: one W_enc2 slice = 4096 x 1KB = 4 MB = one XCD L2.
// XCD-affine swizzle (b & 7 round-robin, learn_hip m09): XCD k owns slices
// [k*spx, (k+1)*spx) and streams ALL rows through one slice before advancing,
// so every W line's ~64 reuses hit the same L2. 4 rows/block, one wave per
// row (feature loop is wave-uniform), lane = 4 cols. Non-temporal output
// stores keep the streamed output from evicting the W slice.
template<int KSLOTS>
__global__ __launch_bounds__(256) void spmm4_kernel(
    const int* __restrict__ sidx, const float* __restrict__ sval,
    const int* __restrict__ scnt,
    const float* __restrict__ W, int ncols,
    const float* __restrict__ bias, float* __restrict__ out, int do_relu,
    int nslices, int nrowblk)
{
  __shared__ int   si[4][KSLOTS];
  __shared__ float sv[4][KSLOTS];
  __shared__ int   cnts[4];

  const int b   = blockIdx.x;
  const int xcd = b & 7;
  const int n   = b >> 3;
  const int spx = nslices >> 3;            // slices per XCD
  const int slice  = xcd * spx + (n / nrowblk);
  const int rowblk = n % nrowblk;

  const int tid = threadIdx.x;
  const int r0 = rowblk * 4;
  if (tid < 4) cnts[tid] = scnt[r0 + tid];
  for (int i = tid; i < 4 * KSLOTS; i += 256) {
    int rl = i / KSLOTS, sl = i % KSLOTS;  // KSLOTS pow2 -> shifts
    si[rl][sl] = sidx[(size_t)(r0 + rl) * KSLOTS + sl];
    sv[rl][sl] = sval[(size_t)(r0 + rl) * KSLOTS + sl];
  }
  __syncthreads();

  const int w = tid >> 6, lane = tid & 63;
  const int row = r0 + w;
  const int c = slice * 256 + lane * 4;
  float4 acc = *(const float4*)&bias[c];
  const int nn = cnts[w];
  const float* Wb = W + c;

  int j = 0;
  for (; j + 4 <= nn; j += 4) {
    int   i0 = si[w][j],     i1 = si[w][j + 1], i2 = si[w][j + 2], i3 = si[w][j + 3];
    float v0 = sv[w][j],     v1 = sv[w][j + 1], v2 = sv[w][j + 2], v3 = sv[w][j + 3];
    const float4 w0 = *(const float4*)&Wb[(size_t)i0 * ncols];
    const float4 w1 = *(const float4*)&Wb[(size_t)i1 * ncols];
    const float4 w2 = *(const float4*)&Wb[(size_t)i2 * ncols];
    const float4 w3 = *(const float4*)&Wb[(size_t)i3 * ncols];
    acc.x += v0 * w0.x; acc.y += v0 * w0.y; acc.z += v0 * w0.z; acc.w += v0 * w0.w;
    acc.x += v1 * w1.x; acc.y += v1 * w1.y; acc.z += v1 * w1.z; acc.w += v1 * w1.w;
    acc.x += v2 * w2.x; acc.y += v2 * w2.y; acc.z += v2 * w2.z; acc.w += v2 * w2.w;
    acc.x += v3 * w3.x; acc.y += v3 * w3.y; acc.z += v3 * w3.z; acc.w += v3 * w3.w;
  }
  for (; j < nn; ++j) {
    float v = sv[w][j];
    const float4 ww = *(const float4*)&Wb[(size_t)si[w][j] * ncols];
    acc.x += v * ww.x; acc.y += v * ww.y; acc.z += v * ww.z; acc.w += v * ww.w;
  }
  if (do_relu) {
    acc.x = relu_pos(acc.x); acc.y = relu_pos(acc.y);
    acc.z = relu_pos(acc.z); acc.w = relu_pos(acc.w);
  }
  f32x4 o;
  o.x = acc.x; o.y = acc.y; o.z = acc.z; o.w = acc.w;
  __builtin_nontemporal_store(o, (f32x4*)&out[(size_t)row * ncols + c]);
}

// ---------------- final aux layer fused with term accumulation ----------------
__global__ __launch_bounds__(256) void spmm_term_kernel(
    const int* __restrict__ sidx, const float* __restrict__ sval,
    const int* __restrict__ scnt, int kslots,
    const float* __restrict__ W, const float* __restrict__ bias,
    const float* __restrict__ x, const float* __restrict__ recon,
    float* __restrict__ accum)
{
  __shared__ int si[512];
  __shared__ float sv[512];
  __shared__ float redf[4];
  const int r = blockIdx.x;
  const int n = scnt[r];
  for (int i = threadIdx.x; i < n; i += 256) {
    si[i] = sidx[(size_t)r * kslots + i];
    sv[i] = sval[(size_t)r * kslots + i];
  }
  __syncthreads();
  const int c0 = threadIdx.x * 4;
  float4 acc = *(const float4*)&bias[c0];
  const float* Wb = W + c0;
  int j = 0;
  for (; j + 4 <= n; j += 4) {
    int   i0 = si[j],     i1 = si[j + 1], i2 = si[j + 2], i3 = si[j + 3];
    float v0 = sv[j],     v1 = sv[j + 1], v2 = sv[j + 2], v3 = sv[j + 3];
    const float4 w0 = *(const float4*)&Wb[(size_t)i0 * 1024];
    const float4 w1 = *(const float4*)&Wb[(size_t)i1 * 1024];
    const float4 w2 = *(const float4*)&Wb[(size_t)i2 * 1024];
    const float4 w3 = *(const float4*)&Wb[(size_t)i3 * 1024];
    acc.x += v0 * w0.x; acc.y += v0 * w0.y; acc.z += v0 * w0.z; acc.w += v0 * w0.w;
    acc.x += v1 * w1.x; acc.y += v1 * w1.y; acc.z += v1 * w1.z; acc.w += v1 * w1.w;
    acc.x += v2 * w2.x; acc.y += v2 * w2.y; acc.z += v2 * w2.z; acc.w += v2 * w2.w;
    acc.x += v3 * w3.x; acc.y += v3 * w3.y; acc.z += v3 * w3.z; acc.w += v3 * w3.w;
  }
  for (; j < n; ++j) {
    float v = sv[j];
    const float4 w = *(const float4*)&Wb[(size_t)si[j] * 1024];
    acc.x += v * w.x; acc.y += v * w.y; acc.z += v * w.z; acc.w += v * w.w;
  }
  const float4 xx = *(const float4*)&x[(size_t)r * 1024 + c0];
  const float4 rc = *(const float4*)&recon[(size_t)r * 1024 + c0];
  float d0 = acc.x - (xx.x - rc.x);
  float d1 = acc.y - (xx.y - rc.y);
  float d2 = acc.z - (xx.z - rc.z);
  float d3 = acc.w - (xx.w - rc.w);
  float local = d0 * d0 + d1 * d1 + d2 * d2 + d3 * d3;
#pragma unroll
  for (int o = 32; o > 0; o >>= 1) local += __shfl_down(local, o, 64);
  if ((threadIdx.x & 63) == 0) redf[threadIdx.x >> 6] = local;
  __syncthreads();
  if (threadIdx.x == 0) atomicAdd(accum, redf[0] + redf[1] + redf[2] + redf[3]);
}

// ---------------- l2 sum ----------------
__global__ __launch_bounds__(256) void l2_kernel(
    const float* __restrict__ x, const float* __restrict__ recon,
    float* __restrict__ accum)
{
  __shared__ float redf[4];
  const int r = blockIdx.x;
  const int c0 = threadIdx.x * 4;
  const float4 xx = *(const float4*)&x[(size_t)r * 1024 + c0];
  const float4 rc = *(const float4*)&recon[(size_t)r * 1024 + c0];
  float d0 = rc.x - xx.x, d1 = rc.y - xx.y, d2 = rc.z - xx.z, d3 = rc.w - xx.w;
  float local = d0 * d0 + d1 * d1 + d2 * d2 + d3 * d3;
#pragma unroll
  for (int o = 32; o > 0; o >>= 1) local += __shfl_down(local, o, 64);
  if ((threadIdx.x & 63) == 0) redf[threadIdx.x >> 6] = local;
  __syncthreads();
  if (threadIdx.x == 0) atomicAdd(accum, redf[0] + redf[1] + redf[2] + redf[3]);
}

// ---------------- dead-feature bookkeeping ----------------
__global__ void mark_active_kernel(const int* __restrict__ idx, const int* __restrict__ cnt,
                                   int kslots, int* __restrict__ active)
{
  const int r = blockIdx.x;
  const int s = threadIdx.x;
  if (s < cnt[r]) active[idx[(size_t)r * kslots + s]] = 1;
}

__global__ void dead_kernel(const int* __restrict__ active, const int* __restrict__ ni,
                            int* __restrict__ dead, int* __restrict__ anyflag)
{
  const int j = blockIdx.x * 256 + threadIdx.x;
  int isdead = (active[j] == 0 && ni[j] >= 2) ? 1 : 0;
  dead[j] = isdead;
  if (isdead) atomicOr(anyflag, 1);
}

__global__ void finalize_kernel(const float* __restrict__ fs, const int* __restrict__ is,
                                float* __restrict__ out)
{
  if (blockIdx.x == 0 && threadIdx.x == 0) {
    const float inv = 1.0f / 2097152.0f;  // mean over B*S*D_MODEL
    float l2 = fs[0] * inv;
    float aux = 0.f;
    if (is[0]) aux += fs[1] * inv;
    if (is[1]) aux += fs[2] * inv;
    if (is[2]) aux += fs[3] * inv;
    out[2097152] = l2 + 0.03125f * aux;
    out[2097153] = l2;
    out[2097154] = aux;
  }
}

// ---------------- host ----------------
extern "C" void kernel_launch(void* const* d_in, const int* in_sizes, int n_in,
                              void* d_out, int out_size, void* d_ws, size_t ws_size,
                              hipStream_t stream)
{
  (void)in_sizes; (void)n_in; (void)out_size; (void)ws_size;
  const float* x      = (const float*)d_in[0];
  const float* W_enc1 = (const float*)d_in[1];
  const float* b_enc1 = (const float*)d_in[2];
  const float* W_enc2 = (const float*)d_in[3];
  const float* b_enc2 = (const float*)d_in[4];
  const float* W_dec2 = (const float*)d_in[5];
  const float* b_dec2 = (const float*)d_in[6];
  const float* W_dec1 = (const float*)d_in[7];
  const float* b_dec1 = (const float*)d_in[8];
  const int* ni0 = (const int*)d_in[9];
  const int* ni1 = (const int*)d_in[10];
  const int* ni2 = (const int*)d_in[11];
  float* out = (float*)d_out;  // [0,2097152) recon; then loss, l2, aux

  char* ws = (char*)d_ws;
  size_t cur = 0;
  auto carve = [&](size_t bytes) -> void* {
    void* p = ws + cur;
    cur += (bytes + 255) & ~(size_t)255;
    return p;
  };
  float* pre0 = (float*)carve((size_t)N_ROWS * DMID * 4);   // 32 MB (also reused for u0/u1)
  float* pre2 = (float*)carve((size_t)N_ROWS * DMID * 4);   // 32 MB
  float* pre1 = (float*)carve((size_t)N_ROWS * DFEAT * 4);  // 128 MB (also reused for g0)

  int*   idx0 = (int*)carve((size_t)N_ROWS * 128 * 4);
  float* val0 = (float*)carve((size_t)N_ROWS * 128 * 4);
  int*   cnt0 = (int*)carve((size_t)N_ROWS * 4);
  int*   idx1 = (int*)carve((size_t)N_ROWS * 64 * 4);
  float* val1 = (float*)carve((size_t)N_ROWS * 64 * 4);
  int*   cnt1 = (int*)carve((size_t)N_ROWS * 4);
  int*   idx2 = (int*)carve((size_t)N_ROWS * 128 * 4);
  float* val2 = (float*)carve((size_t)N_ROWS * 128 * 4);
  int*   cnt2 = (int*)carve((size_t)N_ROWS * 4);

  int*   h0i = (int*)carve((size_t)N_ROWS * 256 * 4);
  float* h0v = (float*)carve((size_t)N_ROWS * 256 * 4);
  int*   h0c = (int*)carve((size_t)N_ROWS * 4);
  int*   h1i = (int*)carve((size_t)N_ROWS * 512 * 4);
  float* h1v = (float*)carve((size_t)N_ROWS * 512 * 4);
  int*   h1c = (int*)carve((size_t)N_ROWS * 4);
  int*   h2i = (int*)carve((size_t)N_ROWS * 256 * 4);
  float* h2v = (float*)carve((size_t)N_ROWS * 256 * 4);
  int*   h2c = (int*)carve((size_t)N_ROWS * 4);

  int*   t0i  = (int*)carve((size_t)N_ROWS * 64 * 4);
  float* t0v  = (float*)carve((size_t)N_ROWS * 64 * 4);
  int*   t0c  = (int*)carve((size_t)N_ROWS * 4);
  int*   t0bi = (int*)carve((size_t)N_ROWS * 128 * 4);
  float* t0bv = (float*)carve((size_t)N_ROWS * 128 * 4);
  int*   t0bc = (int*)carve((size_t)N_ROWS * 4);
  int*   t1bi = (int*)carve((size_t)N_ROWS * 128 * 4);
  float* t1bv = (float*)carve((size_t)N_ROWS * 128 * 4);
  int*   t1bc = (int*)carve((size_t)N_ROWS * 4);

  int* active0 = (int*)carve(DMID * 4);
  int* active1 = (int*)carve(DFEAT * 4);
  int* active2 = (int*)carve(DMID * 4);
  int* dead0   = (int*)carve(DMID * 4);
  int* dead1   = (int*)carve(DFEAT * 4);
  int* dead2   = (int*)carve(DMID * 4);
  float* fscal = (float*)carve(64);  // [0]=l2_sum, [1..3]=aux term sums
  int*   iscal = (int*)carve(64);    // [0..2]=any_dead flags

  // ---- init accumulators / flags ----
  init_zero_kernel<<<64, 256, 0, stream>>>(active0, active1, active2, fscal, iscal);

  // ---- main path ----
  gemm_relu_kernel<<<dim3(DMID / 128, N_ROWS / 128), 256, 0, stream>>>(
      x, W_enc1, b_enc1, pre0, N_ROWS, DMID, DM);
  topk_kernel<4, false><<<N_ROWS, 256, 0, stream>>>(pre0, 128, nullptr, idx0, val0, cnt0);
  // big spmm over W_enc2: 256-col L2-affine kernel (64 slices, 512 row-blocks)
  spmm4_kernel<128><<<(DFEAT / 256) * (N_ROWS / 4), 256, 0, stream>>>(
      idx0, val0, cnt0, W_enc2, DFEAT, b_enc2, pre1, 1, DFEAT / 256, N_ROWS / 4);
  topk_kernel<16, false><<<N_ROWS, 1024, 0, stream>>>(pre1, 64, nullptr, idx1, val1, cnt1);
  spmm4_kernel<64><<<(DMID / 256) * (N_ROWS / 4), 256, 0, stream>>>(
      idx1, val1, cnt1, W_dec2, DMID, b_dec2, pre2, 1, DMID / 256, N_ROWS / 4);
  topk_kernel<4, false><<<N_ROWS, 256, 0, stream>>>(pre2, 128, nullptr, idx2, val2, cnt2);
  spmm_kernel<<<dim3(N_ROWS, 1), 256, 0, stream>>>(
      idx2, val2, cnt2, 128, W_dec1, DM, b_dec1, out, 0);  // recon -> d_out

  l2_kernel<<<N_ROWS, 256, 0, stream>>>(x, out, &fscal[0]);

  // ---- dead-feature masks ----
  mark_active_kernel<<<N_ROWS, 128, 0, stream>>>(idx0, cnt0, 128, active0);
  mark_active_kernel<<<N_ROWS, 64, 0, stream>>>(idx1, cnt1, 64, active1);
  mark_active_kernel<<<N_ROWS, 128, 0, stream>>>(idx2, cnt2, 128, active2);
  dead_kernel<<<DMID / 256, 256, 0, stream>>>(active0, ni0, dead0, &iscal[0]);
  dead_kernel<<<DFEAT / 256, 256, 0, stream>>>(active1, ni1, dead1, &iscal[1]);
  dead_kernel<<<DMID / 256, 256, 0, stream>>>(active2, ni2, dead2, &iscal[2]);

  // ---- aux selections (need pre0/pre1/pre2 intact) ----
  topk_kernel<4, true><<<N_ROWS, 256, 0, stream>>>(pre0, 256, dead0, h0i, h0v, h0c);
  topk_kernel<16, true><<<N_ROWS, 1024, 0, stream>>>(pre1, 512, dead1, h1i, h1v, h1c);
  topk_kernel<4, true><<<N_ROWS, 256, 0, stream>>>(pre2, 256, dead2, h2i, h2v, h2c);

  // ---- aux branch 0: h0 -> W_enc2 -> topk64 -> W_dec2 -> topk128 -> W_dec1 ----
  spmm4_kernel<256><<<(DFEAT / 256) * (N_ROWS / 4), 256, 0, stream>>>(
      h0i, h0v, h0c, W_enc2, DFEAT, b_enc2, pre1 /*g0*/, 1, DFEAT / 256, N_ROWS / 4);
  topk_kernel<16, false><<<N_ROWS, 1024, 0, stream>>>(pre1, 64, nullptr, t0i, t0v, t0c);
  spmm4_kernel<64><<<(DMID / 256) * (N_ROWS / 4), 256, 0, stream>>>(
      t0i, t0v, t0c, W_dec2, DMID, b_dec2, pre0 /*u0*/, 1, DMID / 256, N_ROWS / 4);
  topk_kernel<4, false><<<N_ROWS, 256, 0, stream>>>(pre0, 128, nullptr, t0bi, t0bv, t0bc);
  spmm_term_kernel<<<N_ROWS, 256, 0, stream>>>(
      t0bi, t0bv, t0bc, 128, W_dec1, b_dec1, x, out, &fscal[1]);

  // ---- aux branch 1: h1 -> W_dec2 -> topk128 -> W_dec1 ----
  spmm4_kernel<512><<<(DMID / 256) * (N_ROWS / 4), 256, 0, stream>>>(
      h1i, h1v, h1c, W_dec2, DMID, b_dec2, pre0 /*u1*/, 1, DMID / 256, N_ROWS / 4);
  topk_kernel<4, false><<<N_ROWS, 256, 0, stream>>>(pre0, 128, nullptr, t1bi, t1bv, t1bc);
  spmm_term_kernel<<<N_ROWS, 256, 0, stream>>>(
      t1bi, t1bv, t1bc, 128, W_dec1, b_dec1, x, out, &fscal[2]);

  // ---- aux branch 2: h2 -> W_dec1 ----
  spmm_term_kernel<<<N_ROWS, 256, 0, stream>>>(
      h2i, h2v, h2c, 256, W_dec1, b_dec1, x, out, &fscal[3]);

  // ---- scalars ----
  finalize_kernel<<<1, 64, 0, stream>>>(fscal, iscal, out);
}